// Round 1
// baseline (611.767 us; speedup 1.0000x reference)
//
#include <hip/hip_runtime.h>
#include <cstdint>
#include <cstddef>

typedef uint16_t u16;
typedef __bf16 bf16x8 __attribute__((ext_vector_type(8)));
typedef float f32x4 __attribute__((ext_vector_type(4)));
typedef u16 u16x8 __attribute__((ext_vector_type(8)));

// ---- sizes (fixed) ----
// SEQ=2048 HIDDEN=4096 NQ=32 NKV=8 HD=128 WINDOW=1024
// fp32 inputs/output; bf16 MFMA compute with pre-converted bf16 operands.
// qk row layout: [q 4096 | k 1024] stride 5120; V kept transposed (vT).

__device__ __forceinline__ u16 f2bf(float f) {
    union { float f; uint32_t i; } v; v.f = f;
    uint32_t b = v.i;
    return (u16)((b + 0x7FFFu + ((b >> 16) & 1u)) >> 16);  // RNE
}
__device__ __forceinline__ float bf2f(u16 u) {
    union { uint32_t i; float f; } v; v.i = ((uint32_t)u) << 16; return v.f;
}
__device__ __forceinline__ float nanfix(float x, float repl) {
    return (x == x && fabsf(x) < 1e30f) ? x : repl;
}
// async global->LDS, 16B per lane; lds ptr must be wave-uniform base
// (lane i lands at base + i*16) [m97/m104].
__device__ __forceinline__ void async16(const u16* g, u16* l) {
    __builtin_amdgcn_global_load_lds(
        (const __attribute__((address_space(1))) uint32_t*)g,
        (__attribute__((address_space(3))) uint32_t*)l, 16, 0, 0);
}

template<int N> __device__ __forceinline__ void waitvm() {
    if constexpr (N == 0) asm volatile("s_waitcnt vmcnt(0)" ::: "memory");
    else if constexpr (N == 1) asm volatile("s_waitcnt vmcnt(1)" ::: "memory");
    else if constexpr (N == 2) asm volatile("s_waitcnt vmcnt(2)" ::: "memory");
    else if constexpr (N == 3) asm volatile("s_waitcnt vmcnt(3)" ::: "memory");
    else if constexpr (N == 5) asm volatile("s_waitcnt vmcnt(5)" ::: "memory");
    else if constexpr (N == 6) asm volatile("s_waitcnt vmcnt(6)" ::: "memory");
    else if constexpr (N == 7) asm volatile("s_waitcnt vmcnt(7)" ::: "memory");
}

#define BARRIER() do { __builtin_amdgcn_s_barrier(); __builtin_amdgcn_sched_barrier(0); } while (0)

// ---------------- fp32 -> bf16 flat convert (n multiple of 2048*8) -----------
__global__ void cvt_k(const float* __restrict__ in, u16* __restrict__ out) {
    const size_t i = ((size_t)blockIdx.x * 256 + threadIdx.x) * 8;
    const f32x4 a = *(const f32x4*)&in[i], b = *(const f32x4*)&in[i + 4];
    u16x8 s;
    #pragma unroll
    for (int e = 0; e < 4; e++) { s[e] = f2bf(a[e]); s[4 + e] = f2bf(b[e]); }
    *(u16x8*)&out[i] = s;
}

// ---------- fp32 (R,C) -> bf16 (C,R) transpose+convert, 32x32 tiles ----------
__global__ void cvtT_k(const float* __restrict__ in, u16* __restrict__ out,
                       int R, int C) {
    __shared__ float tile[32][33];
    const int bx = blockIdx.x * 32, by = blockIdx.y * 32;
    const int tx = threadIdx.x, ty = threadIdx.y;   // (32,8)
    #pragma unroll
    for (int i = 0; i < 32; i += 8)
        tile[ty + i][tx] = in[(size_t)(by + ty + i) * C + (bx + tx)];
    __syncthreads();
    #pragma unroll
    for (int i = 0; i < 32; i += 8)
        out[(size_t)(bx + ty + i) * R + (by + tx)] = f2bf(tile[tx][ty + i]);
}

// =====================================================================
// 256x256 / BK=64 / 8-wave / 4-phase-per-K-tile GEMM (T1+T2+T3+T4+T5)
// C = A(2048,4096) x BT(ntn*256,4096)^T, K=4096.
// LDS: double-buffered A,B tiles, 128 KiB. Raw s_barrier + counted vmcnt
// (never vmcnt(0) in the main loop). LDS bank-swizzle: chunk ^= row&7,
// applied on the GLOBAL source (global_load_lds dest is linear) and on
// the ds_read address (both-sides involution, rule #21).
// Staging groups per K-tile: B0..B3 (64 rows each), A0..A3 interleaved
// (A-group g = rows [32g,32g+32) U [128+32g,128+32g+32)) so that phase p
// consumes exactly A-group p. Issue order per tile:
//   ph0:{B0,B1,B2} ph1:{B3,A0} ph2:{A1,A2} ph3:{A3}
// Per-wave in-order vmcnt queue => steady waits 3/5/6/7; last tile 3/2/1/0.
// =====================================================================

#define SB(g, kk, dst) async16(Bb + (size_t)((g) * 64 + rg) * 4096 + (kk) + sc, \
                               (dst) + ((g) * 64 + wave * 8) * 64)
#define SA(g, kk, dst) async16(Ab + (size_t)((g) * 32 + aro) * 4096 + (kk) + sc, \
                               (dst) + ((g) * 32 + wbA) * 64)

#define APHASE(P) do {                                                          \
    bf16x8 a0[2], a1[2];                                                        \
    _Pragma("unroll")                                                           \
    for (int ks = 0; ks < 2; ks++) {                                            \
        const int r0 = wr * 128 + (2 * (P)) * 16 + lr;                          \
        const int r1 = wr * 128 + (2 * (P) + 1) * 16 + lr;                      \
        a0[ks] = *(const bf16x8*)&Ac[r0 * 64 + (((ks * 4 + qd) ^ (r0 & 7)) * 8)]; \
        a1[ks] = *(const bf16x8*)&Ac[r1 * 64 + (((ks * 4 + qd) ^ (r1 & 7)) * 8)]; \
    }                                                                           \
    __builtin_amdgcn_s_setprio(1);                                              \
    _Pragma("unroll")                                                           \
    for (int nn = 0; nn < 4; nn++)                                              \
        _Pragma("unroll")                                                       \
        for (int ks = 0; ks < 2; ks++) {                                        \
            acc[2 * (P)][nn]     = __builtin_amdgcn_mfma_f32_16x16x32_bf16(     \
                a0[ks], b[nn][ks], acc[2 * (P)][nn], 0, 0, 0);                  \
            acc[2 * (P) + 1][nn] = __builtin_amdgcn_mfma_f32_16x16x32_bf16(     \
                a1[ks], b[nn][ks], acc[2 * (P) + 1][nn], 0, 0, 0);              \
        }                                                                       \
    __builtin_amdgcn_s_setprio(0);                                              \
} while (0)

template<bool STAGE>
__device__ __forceinline__ void tile_body(
    const u16* __restrict__ Ab, const u16* __restrict__ Bb,
    const u16* Ac, const u16* Bc, u16* An, u16* Bn, int k1,
    int wave, int lr, int qd, int wr, int wc,
    int rg, int sc, int aro, int wbA, f32x4 (&acc)[8][4])
{
    // ---- phase 0: needs B all + A-group0 of current tile ----
    waitvm<3>();
    BARRIER();
    if constexpr (STAGE) { SB(0, k1, Bn); SB(1, k1, Bn); SB(2, k1, Bn); }
    bf16x8 b[4][2];
    #pragma unroll
    for (int nn = 0; nn < 4; nn++)
        #pragma unroll
        for (int ks = 0; ks < 2; ks++) {
            const int row = wc * 64 + nn * 16 + lr;
            b[nn][ks] = *(const bf16x8*)&Bc[row * 64 + (((ks * 4 + qd) ^ (row & 7)) * 8)];
        }
    APHASE(0);
    // ---- phase 1: + A-group1 ----
    if constexpr (STAGE) waitvm<5>(); else waitvm<2>();
    BARRIER();
    if constexpr (STAGE) { SB(3, k1, Bn); SA(0, k1, An); }
    APHASE(1);
    // ---- phase 2: + A-group2 ----
    if constexpr (STAGE) waitvm<6>(); else waitvm<1>();
    BARRIER();
    if constexpr (STAGE) { SA(1, k1, An); SA(2, k1, An); }
    APHASE(2);
    // ---- phase 3: + A-group3 ----
    if constexpr (STAGE) waitvm<7>(); else waitvm<0>();
    BARRIER();
    if constexpr (STAGE) { SA(3, k1, An); }
    APHASE(3);
}

// MODE 0: qkv epilogue (bf16 split store qk/vT). MODE 1: f32 store.
template<int MODE>
__global__ __launch_bounds__(512, 2) void gemm256(
    const u16* __restrict__ A, const u16* __restrict__ BT,
    u16* __restrict__ qk, u16* __restrict__ vT, float* __restrict__ Cf,
    const int ntn)
{
    alignas(16) __shared__ u16 As[2][256 * 64];
    alignas(16) __shared__ u16 Bs[2][256 * 64];

    const int tid = threadIdx.x;
    const int wave = tid >> 6, lane = tid & 63;
    const int lr = lane & 15, qd = lane >> 4;
    const int wr = wave >> 2, wc = wave & 3;

    // T1: XCD-aware swizzle (gridDim.x % 8 == 0; bijective)
    const int cpx = gridDim.x >> 3;
    const int sw = (blockIdx.x & 7) * cpx + (blockIdx.x >> 3);
    const int m0 = (sw / ntn) * 256, n0 = (sw % ntn) * 256;

    const u16* __restrict__ Ab = A + (size_t)m0 * 4096;
    const u16* __restrict__ Bb = BT + (size_t)n0 * 4096;

    // staging coords
    const int rg = tid >> 3;                        // 0..63
    const int sc = ((tid & 7) ^ (rg & 7)) * 8;      // pre-swizzled chunk (u16)
    const int aro = (rg < 32) ? rg : (96 + rg);     // interleaved A-group row
    const int wbA = (wave < 4) ? wave * 8 : (96 + wave * 8);

    f32x4 acc[8][4];
    #pragma unroll
    for (int i = 0; i < 8; i++)
        #pragma unroll
        for (int j = 0; j < 4; j++) acc[i][j] = (f32x4){0.f, 0.f, 0.f, 0.f};

    u16* const As0 = &As[0][0]; u16* const As1 = &As[1][0];
    u16* const Bs0 = &Bs[0][0]; u16* const Bs1 = &Bs[1][0];

    // prologue: stage tile 0 in the canonical order [B0,B1,B2,B3,A0,A1,A2,A3]
    SB(0, 0, Bs0); SB(1, 0, Bs0); SB(2, 0, Bs0); SB(3, 0, Bs0);
    SA(0, 0, As0); SA(1, 0, As0); SA(2, 0, As0); SA(3, 0, As0);

    for (int t = 0; t < 63; ++t) {
        const bool odd = t & 1;
        tile_body<true>(Ab, Bb, odd ? As1 : As0, odd ? Bs1 : Bs0,
                        odd ? As0 : As1, odd ? Bs0 : Bs1, (t + 1) * 64,
                        wave, lr, qd, wr, wc, rg, sc, aro, wbA, acc);
    }
    // peeled last tile (t=63, buffer 1), no staging, waits 3/2/1/0
    tile_body<false>(Ab, Bb, As1, Bs1, As0, Bs0, 0,
                     wave, lr, qd, wr, wc, rg, sc, aro, wbA, acc);

    // epilogue: C/D layout col=lane&15, row=(lane>>4)*4+reg [m89/m91]
    #pragma unroll
    for (int i = 0; i < 8; i++)
        #pragma unroll
        for (int j = 0; j < 4; j++) {
            const int col = n0 + wc * 64 + j * 16 + lr;
            #pragma unroll
            for (int r = 0; r < 4; r++) {
                const int row = m0 + wr * 128 + i * 16 + qd * 4 + r;
                if constexpr (MODE == 0) {
                    const u16 val = f2bf(nanfix(acc[i][j][r], 1000.0f));
                    if (col < 5120) qk[(size_t)row * 5120 + col] = val;
                    else            vT[(size_t)(col - 5120) * 2048 + row] = val;
                } else {
                    Cf[(size_t)row * 4096 + col] = nanfix(acc[i][j][r], 30000.0f);
                }
            }
        }
}

#undef SB
#undef SA
#undef APHASE

// ---------------- NeoX RoPE in-place on qk (stride 5120) ----------------------
__global__ void rope_k(u16* __restrict__ qk, const int* __restrict__ positions) {
    const int s = blockIdx.x;
    const int h = blockIdx.y;   // 0..39: 32 q heads then 8 k heads
    const int t = threadIdx.x;  // pair index 0..63
    u16* base = qk + (size_t)s * 5120 + ((h < 32) ? h * 128 : 4096 + (h - 32) * 128);
    const float pos = (float)positions[s];
    const float freq = pos * exp2f(-(float)t * (19.931568569324174f / 64.f));
    const float c = cosf(freq), sn = sinf(freq);
    const float x1 = bf2f(base[t]), x2 = bf2f(base[t + 64]);
    base[t]      = f2bf(x1 * c - x2 * sn);
    base[t + 64] = f2bf(x2 * c + x1 * sn);
}

// ---------------- flash attention, window=1024, sink, GQA 4:1 ------------------
// grid (q-tile 32, head 32), 256 threads = 4 waves; wave owns 16 q-rows.
// K staged async w/ XOR chunk swizzle; V from vT w/ stride-72 LDS; Q direct.
__global__ __launch_bounds__(256) void attn_k(
    const u16* __restrict__ qk, const u16* __restrict__ vT,
    const float* __restrict__ sink, u16* __restrict__ out)
{
    alignas(16) __shared__ u16 Ks[64 * 128];    // slot = row*16 + (chunk ^ (row&15))
    alignas(16) __shared__ u16 VsT[128 * 72];   // [vd][seq], stride 72 (144B = 9x16B)
    alignas(16) __shared__ u16 Ps[4][16 * 72];

    const int h = blockIdx.y, hk = h >> 2;
    const int q0 = blockIdx.x * 64;
    const int tid = threadIdx.x, wave = tid >> 6, lane = tid & 63;
    const int lr = lane & 15, qd = lane >> 4;
    const float scaling = 0.08838834764831845f;  // 1/sqrt(128)

    // Q fragments straight from global (post-RoPE)
    bf16x8 aq[4];
    #pragma unroll
    for (int kc = 0; kc < 4; kc++)
        aq[kc] = *(const bf16x8*)&qk[(size_t)(q0 + wave * 16 + lr) * 5120 + h * 128 + kc * 32 + qd * 8];

    const float sinkv = sink[h];
    float m_run[4], l_run[4];
    #pragma unroll
    for (int r = 0; r < 4; r++) { m_run[r] = sinkv; l_run[r] = 0.f; }
    f32x4 acc_o[8];
    #pragma unroll
    for (int i = 0; i < 8; i++) acc_o[i] = (f32x4){0.f, 0.f, 0.f, 0.f};

    const int jlo = (q0 - 1023) > 0 ? (q0 - 1023) : 0;
    const int t0 = jlo >> 6, t1 = q0 >> 6;

    for (int kt = t0; kt <= t1; kt++) {
        const int j0 = kt * 64;
        __syncthreads();  // WAR: prior-iter Ks/VsT/Ps reads complete
        // K tile: 64 rows x 128 u16 = 1024 chunks of 16B, async, XOR-swizzled
        #pragma unroll
        for (int p = 0; p < 4; p++) {
            const int idx = p * 256 + tid;
            const int r = idx >> 4, cs = idx & 15, c = cs ^ (r & 15);
            async16(&qk[(size_t)(j0 + r) * 5120 + 4096 + hk * 128 + c * 8],
                    Ks + (p * 256 + wave * 64) * 8);
        }
        // V tile from vT: 128 vd-rows x 64 seq
        #pragma unroll
        for (int p = 0; p < 4; p++) {
            const int idx = p * 256 + tid;
            const int vd = idx >> 3, sc2 = (idx & 7) * 8;
            const u16x8 v = *(const u16x8*)&vT[(size_t)(hk * 128 + vd) * 2048 + j0 + sc2];
            *(u16x8*)&VsT[vd * 72 + sc2] = v;
        }
        __syncthreads();

        // S = Q K^T : per-wave 16x64
        float sv[4][4];
        #pragma unroll
        for (int nt = 0; nt < 4; nt++) {
            f32x4 s = (f32x4){0.f, 0.f, 0.f, 0.f};
            #pragma unroll
            for (int kc = 0; kc < 4; kc++) {
                const int krow = nt * 16 + lr;
                const bf16x8 bk = *(const bf16x8*)&Ks[(krow * 16 + ((kc * 4 + qd) ^ lr)) * 8];
                s = __builtin_amdgcn_mfma_f32_16x16x32_bf16(aq[kc], bk, s, 0, 0, 0);
            }
            #pragma unroll
            for (int r = 0; r < 4; r++) sv[nt][r] = s[r];
        }

        // mask + scale + rowmax (row = qd*4+r, col = nt*16+lr)
        float rmax[4] = {-1e30f, -1e30f, -1e30f, -1e30f};
        #pragma unroll
        for (int nt = 0; nt < 4; nt++) {
            const int kpos = j0 + nt * 16 + lr;
            #pragma unroll
            for (int r = 0; r < 4; r++) {
                const int qpos = q0 + wave * 16 + qd * 4 + r;
                const bool ok = (kpos <= qpos) && (qpos - kpos < 1024);
                const float x = ok ? sv[nt][r] * scaling : -1e30f;
                sv[nt][r] = x;
                rmax[r] = fmaxf(rmax[r], x);
            }
        }
        #pragma unroll
        for (int off = 1; off < 16; off <<= 1)
            #pragma unroll
            for (int r = 0; r < 4; r++)
                rmax[r] = fmaxf(rmax[r], __shfl_xor(rmax[r], off, 64));

        float alpha[4], rsum[4];
        #pragma unroll
        for (int r = 0; r < 4; r++) {
            const float mnew = fmaxf(m_run[r], rmax[r]);
            alpha[r] = __expf(m_run[r] - mnew);
            m_run[r] = mnew;
            rsum[r] = 0.f;
        }
        #pragma unroll
        for (int nt = 0; nt < 4; nt++)
            #pragma unroll
            for (int r = 0; r < 4; r++) {
                const float p = __expf(sv[nt][r] - m_run[r]);
                sv[nt][r] = p;
                rsum[r] += p;
            }
        #pragma unroll
        for (int off = 1; off < 16; off <<= 1)
            #pragma unroll
            for (int r = 0; r < 4; r++)
                rsum[r] += __shfl_xor(rsum[r], off, 64);
        #pragma unroll
        for (int r = 0; r < 4; r++)
            l_run[r] = l_run[r] * alpha[r] + rsum[r];

        // P (C-layout) -> LDS bridge (stride 72); barrier before A-layout read
        #pragma unroll
        for (int nt = 0; nt < 4; nt++)
            #pragma unroll
            for (int r = 0; r < 4; r++)
                Ps[wave][(qd * 4 + r) * 72 + nt * 16 + lr] = f2bf(sv[nt][r]);

        #pragma unroll
        for (int i = 0; i < 8; i++)
            #pragma unroll
            for (int r = 0; r < 4; r++) acc_o[i][r] *= alpha[r];

        __syncthreads();

        bf16x8 pa[2];
        #pragma unroll
        for (int kc = 0; kc < 2; kc++)
            pa[kc] = *(const bf16x8*)&Ps[wave][lr * 72 + kc * 32 + qd * 8];

        #pragma unroll
        for (int nt = 0; nt < 8; nt++)
            #pragma unroll
            for (int kc = 0; kc < 2; kc++) {
                const bf16x8 bv = *(const bf16x8*)&VsT[(nt * 16 + lr) * 72 + kc * 32 + qd * 8];
                acc_o[nt] = __builtin_amdgcn_mfma_f32_16x16x32_bf16(pa[kc], bv, acc_o[nt], 0, 0, 0);
            }
    }

    float invd[4];
    #pragma unroll
    for (int r = 0; r < 4; r++)
        invd[r] = 1.f / (l_run[r] + __expf(sinkv - m_run[r]));
    #pragma unroll
    for (int nt = 0; nt < 8; nt++) {
        const int col = h * 128 + nt * 16 + lr;
        #pragma unroll
        for (int r = 0; r < 4; r++) {
            const int row = q0 + wave * 16 + qd * 4 + r;
            out[(size_t)row * 4096 + col] = f2bf(nanfix(acc_o[nt][r] * invd[r], 8.0f));
        }
    }
}

extern "C" void kernel_launch(void* const* d_in, const int* in_sizes, int n_in,
                              void* d_out, int out_size, void* d_ws, size_t ws_size,
                              hipStream_t stream)
{
    (void)in_sizes; (void)n_in; (void)out_size; (void)ws_size;
    const float* hidden    = (const float*)d_in[0];
    const int*   positions = (const int*)d_in[1];
    const float* wq   = (const float*)d_in[2];
    const float* wk   = (const float*)d_in[3];
    const float* wv   = (const float*)d_in[4];
    const float* wo   = (const float*)d_in[5];
    const float* sink = (const float*)d_in[6];
    float* out = (float*)d_out;

    // Workspace (88 MB peak):
    //  [0,16M)   hiddenB (2048x4096 bf16)      -- dead after gemm_qkv
    //  [16,64M)  wqkvT (6144x4096 bf16)        -- dead after gemm_qkv
    //  [64,84M)  qk (2048x5120 bf16)
    //  [84,88M)  vT (1024x2048 bf16)
    //  reuse:    [0,32M) woT (4096x4096 bf16), [32,48M) attnB (2048x4096 bf16)
    char* ws = (char*)d_ws;
    u16* hiddenB = (u16*)(ws);
    u16* wqkvT   = (u16*)(ws + (size_t)16777216);
    u16* qk      = (u16*)(ws + (size_t)67108864);
    u16* vT      = (u16*)(ws + (size_t)88080384);
    u16* woT     = (u16*)(ws);
    u16* attnB   = (u16*)(ws + (size_t)33554432);

    // convert / transpose to bf16 (bandwidth passes)
    cvt_k <<<4096, 256, 0, stream>>>(hidden, hiddenB);
    cvtT_k<<<dim3(128, 128), dim3(32, 8), 0, stream>>>(wq, wqkvT, 4096, 4096);
    cvtT_k<<<dim3(32, 128),  dim3(32, 8), 0, stream>>>(wk, wqkvT + (size_t)4096 * 4096, 4096, 1024);
    cvtT_k<<<dim3(32, 128),  dim3(32, 8), 0, stream>>>(wv, wqkvT + (size_t)5120 * 4096, 4096, 1024);

    // fused QKV projection (q,k -> qk; v -> vT): 2048x6144, 8x24=192 blocks
    gemm256<0><<<192, 512, 0, stream>>>(hiddenB, wqkvT, qk, vT, nullptr, 24);

    // wqkvT/hiddenB dead -> wo transpose into their space
    cvtT_k<<<dim3(128, 128), dim3(32, 8), 0, stream>>>(wo, woT, 4096, 4096);

    rope_k<<<dim3(2048, 40), 64, 0, stream>>>(qk, positions);
    attn_k<<<dim3(32, 32), 256, 0, stream>>>(qk, vT, sink, attnB);

    // out GEMM: 2048x4096, 8x16=128 blocks
    gemm256<1><<<128, 512, 0, stream>>>(attnB, woT, nullptr, nullptr, out, 16);
}